// Round 1
// baseline (96.253 us; speedup 1.0000x reference)
//
#include <hip/hip_runtime.h>
#include <hip/hip_bf16.h>
#include <math.h>

typedef unsigned short ushort_t;
typedef unsigned int uint_t;

#define C_CURV 1.5f
#define SQRT_C 1.22474487139158905f
#define TEMP_ 0.1f

typedef __attribute__((ext_vector_type(8))) short short8;
typedef __attribute__((ext_vector_type(4))) float f32x4;

static __device__ __forceinline__ ushort_t f2bf(float f) {
  union { float f; uint_t u; } v; v.f = f;
  uint_t u = v.u;
  // round-to-nearest-even fp32 -> bf16 (inputs are finite)
  uint_t r = (u + 0x7FFFu + ((u >> 16) & 1u)) >> 16;
  return (ushort_t)r;
}

static __device__ __forceinline__ float gelu_exact(float x) {
  return 0.5f * x * (1.0f + erff(x * 0.70710678118654752f));
}

// ---------------- convert x (fp32) -> bf16 ----------------
__global__ void k_cvt_x(const float* __restrict__ x, ushort_t* __restrict__ xb, int n4) {
  int i = blockIdx.x * blockDim.x + threadIdx.x;
  if (i >= n4) return;
  float4 v = reinterpret_cast<const float4*>(x)[i];
  ushort4 o;
  o.x = f2bf(v.x); o.y = f2bf(v.y); o.z = f2bf(v.z); o.w = f2bf(v.w);
  reinterpret_cast<ushort4*>(xb)[i] = o;
}

// ---------------- GEMM: partial[br][ks][64][N] = A_bf16(64xK chunk) * W_fp32(KxN chunk) ----------------
// Wave computes 64x16 output tile via 4x mfma_16x16x32_bf16 per 32-k step.
// A/B fragments both use k-map kappa(g,j) = 8*g + j (any consistent bijection is valid).
__global__ __launch_bounds__(256) void k_gemm(
    const ushort_t* __restrict__ Abase, long a_br_stride,
    const float* __restrict__ Wg, const float* __restrict__ Ws,
    float* __restrict__ partial, int N, int K, int kchunk)
{
  const int tn = blockIdx.x, ks = blockIdx.y, br = blockIdx.z;
  const int KS = gridDim.y;
  const ushort_t* A = Abase + (long)br * a_br_stride;
  const float* W = br ? Ws : Wg;
  const int lane = threadIdx.x & 63;
  const int wave = threadIdx.x >> 6;
  const int c = lane & 15;
  const int g = lane >> 4;
  const int n0 = tn * 64 + wave * 16 + c;
  const int k0 = ks * kchunk;

  const float* wp = W + (long)(k0 + 8 * g) * N + n0;
  const ushort_t* ap = A + (long)c * K + k0 + 8 * g;
  const long wstep = (long)32 * N;

  f32x4 acc[4];
  #pragma unroll
  for (int mi = 0; mi < 4; ++mi) acc[mi] = f32x4{0.f, 0.f, 0.f, 0.f};

  for (int kk = 0; kk < kchunk; kk += 64) {
    float bw0[8], bw1[8];
    #pragma unroll
    for (int j = 0; j < 8; ++j) bw0[j] = wp[(long)j * N];
    #pragma unroll
    for (int j = 0; j < 8; ++j) bw1[j] = wp[wstep + (long)j * N];
    short8 af0[4], af1[4];
    #pragma unroll
    for (int mi = 0; mi < 4; ++mi) {
      af0[mi] = *reinterpret_cast<const short8*>(ap + (long)mi * 16 * K);
      af1[mi] = *reinterpret_cast<const short8*>(ap + (long)mi * 16 * K + 32);
    }
    wp += 2 * wstep;
    ap += 64;
    short8 bf0, bf1;
    #pragma unroll
    for (int j = 0; j < 8; ++j) bf0[j] = (short)f2bf(bw0[j]);
    #pragma unroll
    for (int j = 0; j < 8; ++j) bf1[j] = (short)f2bf(bw1[j]);
    #pragma unroll
    for (int mi = 0; mi < 4; ++mi)
      acc[mi] = __builtin_amdgcn_mfma_f32_16x16x32_bf16(af0[mi], bf0, acc[mi], 0, 0, 0);
    #pragma unroll
    for (int mi = 0; mi < 4; ++mi)
      acc[mi] = __builtin_amdgcn_mfma_f32_16x16x32_bf16(af1[mi], bf1, acc[mi], 0, 0, 0);
  }

  // D layout (m89-verified): col = lane&15, row = 4*(lane>>4) + reg
  float* po = partial + (long)(br * KS + ks) * 64 * N;
  #pragma unroll
  for (int mi = 0; mi < 4; ++mi)
    #pragma unroll
    for (int q = 0; q < 4; ++q) {
      int b = 16 * mi + 4 * g + q;
      po[(long)b * N + n0] = acc[mi][q];
    }
}

// ---------------- reduce K-split partials + bias + exact GELU -> bf16 activations ----------------
__global__ void k_reduce_gelu(const float* __restrict__ partial,
    const float* __restrict__ bg, const float* __restrict__ bs,
    ushort_t* __restrict__ hb, int N, int KS, int total4)
{
  int i = blockIdx.x * blockDim.x + threadIdx.x;
  if (i >= total4) return;
  int perbr = 64 * N / 4;
  int br = i / perbr;
  int rem = i - br * perbr;
  const float4* pp = reinterpret_cast<const float4*>(partial) + (long)br * KS * perbr + rem;
  float4 s = {0.f, 0.f, 0.f, 0.f};
  for (int ks = 0; ks < KS; ++ks) {
    float4 t = pp[(long)ks * perbr];
    s.x += t.x; s.y += t.y; s.z += t.z; s.w += t.w;
  }
  int n4 = rem % (N / 4);
  float4 bv = reinterpret_cast<const float4*>(br ? bs : bg)[n4];
  s.x += bv.x; s.y += bv.y; s.z += bv.z; s.w += bv.w;
  ushort4 o;
  o.x = f2bf(gelu_exact(s.x));
  o.y = f2bf(gelu_exact(s.y));
  o.z = f2bf(gelu_exact(s.z));
  o.w = f2bf(gelu_exact(s.w));
  reinterpret_cast<ushort4*>(hb)[i] = o;
}

// ---------------- layer-3 reduce + bias + expmap0 -> hyp (bf16) and y2 = ||hyp||^2 ----------------
__global__ __launch_bounds__(256) void k_expmap(const float* __restrict__ partial,
    const float* __restrict__ b3g, const float* __restrict__ b3s,
    ushort_t* __restrict__ hypb, float* __restrict__ y2, int KS)
{
  int b = blockIdx.x, br = blockIdx.y, d = threadIdx.x;
  const float* pp = partial + (long)(br * KS) * 64 * 256 + (long)b * 256 + d;
  float s = 0.f;
  for (int ks = 0; ks < KS; ++ks) s += pp[(long)ks * 64 * 256];
  s += (br ? b3s : b3g)[d];

  float v = s * s;
  #pragma unroll
  for (int off = 1; off < 64; off <<= 1) v += __shfl_xor(v, off);
  __shared__ float red[4];
  __shared__ float n2s;
  if ((threadIdx.x & 63) == 0) red[threadIdx.x >> 6] = v;
  __syncthreads();
  if (threadIdx.x == 0) n2s = red[0] + red[1] + red[2] + red[3];
  __syncthreads();
  float n = fmaxf(sqrtf(n2s), 1e-15f);
  float sn = SQRT_C * n;
  float t = tanhf(sn);
  float scale = t / sn;
  hypb[((long)br * 64 + b) * 256 + d] = f2bf(s * scale);
  if (threadIdx.x == 0) y2[br * 64 + b] = t * t / C_CURV;
}

// ---------------- Poincare distance logits ----------------
// s[b][p] = <hyp_b, proto_p> via MFMA (bf16); x2[p] accumulated in fp32 from the same loads.
__global__ __launch_bounds__(256) void k_dist(const float* __restrict__ pg,
    const float* __restrict__ ps, const ushort_t* __restrict__ hypb,
    const float* __restrict__ y2, float* __restrict__ out)
{
  int w = blockIdx.x * 4 + (threadIdx.x >> 6);
  const int lane = threadIdx.x & 63;
  const int c = lane & 15, g = lane >> 4;
  const float* protos; const ushort_t* A; const float* y2p; float* ob; int P;
  if (w < 32) {
    protos = pg; P = 500; A = hypb; y2p = y2; ob = out;
  } else {
    w -= 32;
    if (w >= 313) return;
    protos = ps; P = 5000; A = hypb + 64 * 256; y2p = y2 + 64; ob = out + 64 * 500;
  }
  int p0 = w * 16;
  int p = p0 + c;
  int pc = min(p, P - 1);
  const float* pp = protos + (long)pc * 256 + 8 * g;
  const ushort_t* ap = A + (long)c * 256 + 8 * g;

  f32x4 acc[4];
  #pragma unroll
  for (int mi = 0; mi < 4; ++mi) acc[mi] = f32x4{0.f, 0.f, 0.f, 0.f};
  float x2p = 0.f;

  for (int s8 = 0; s8 < 8; ++s8) {
    float pw[8];
    #pragma unroll
    for (int j = 0; j < 8; ++j) pw[j] = pp[j];
    pp += 32;
    short8 bfr;
    #pragma unroll
    for (int j = 0; j < 8; ++j) { x2p += pw[j] * pw[j]; bfr[j] = (short)f2bf(pw[j]); }
    #pragma unroll
    for (int mi = 0; mi < 4; ++mi) {
      short8 af = *reinterpret_cast<const short8*>(ap + (long)mi * 16 * 256 + s8 * 32);
      acc[mi] = __builtin_amdgcn_mfma_f32_16x16x32_bf16(af, bfr, acc[mi], 0, 0, 0);
    }
  }
  x2p += __shfl_xor(x2p, 16);
  x2p += __shfl_xor(x2p, 32);
  const float x2 = x2p;
  const float bb = 1.f - C_CURV * x2;
  const float LC = -2.f / (SQRT_C * TEMP_);

  if (p < P) {
    #pragma unroll
    for (int mi = 0; mi < 4; ++mi)
      #pragma unroll
      for (int q = 0; q < 4; ++q) {
        int b = 16 * mi + 4 * g + q;
        float xy = -acc[mi][q];
        float y2v = y2p[b];
        float a = 1.f + 2.f * C_CURV * xy + C_CURV * y2v;
        float den = fabsf(1.f + 2.f * C_CURV * xy + C_CURV * C_CURV * x2 * y2v);
        den = fmaxf(den, 1e-15f);
        float num2 = a * a * x2 + 2.f * a * bb * xy + bb * bb * y2v;
        num2 = fmaxf(num2, 0.f);
        float r = SQRT_C * sqrtf(num2) / den;
        r = fminf(r, 1.f - 1e-5f);
        r = fmaxf(r, 0.f);
        ob[(long)b * P + p] = LC * atanhf(r);
      }
  }
}

// ---------------- launch ----------------
extern "C" void kernel_launch(void* const* d_in, const int* in_sizes, int n_in,
                              void* d_out, int out_size, void* d_ws, size_t ws_size,
                              hipStream_t stream) {
  const float* x   = (const float*)d_in[0];
  const float* pg  = (const float*)d_in[1];
  const float* ps  = (const float*)d_in[2];
  const float* w1g = (const float*)d_in[3];
  const float* b1g = (const float*)d_in[4];
  const float* w2g = (const float*)d_in[5];
  const float* b2g = (const float*)d_in[6];
  const float* w3g = (const float*)d_in[7];
  const float* b3g = (const float*)d_in[8];
  const float* w1s = (const float*)d_in[9];
  const float* b1s = (const float*)d_in[10];
  const float* w2s = (const float*)d_in[11];
  const float* b2s = (const float*)d_in[12];
  const float* w3s = (const float*)d_in[13];
  const float* b3s = (const float*)d_in[14];
  float* out = (float*)d_out;
  char* ws = (char*)d_ws;

  float*    partial = (float*)   (ws + 0);         // 8 MB max (layer2: 2*4*64*4096*4)
  ushort_t* xb      = (ushort_t*)(ws + 8388608);   // 64*768 bf16
  ushort_t* h1b     = (ushort_t*)(ws + 8486912);   // 2*64*4096 bf16
  ushort_t* h2b     = (ushort_t*)(ws + 9535488);   // 2*64*4096 bf16
  ushort_t* hypb    = (ushort_t*)(ws + 10584064);  // 2*64*256 bf16
  float*    y2      = (float*)   (ws + 10649600);  // 2*64 fp32

  (void)in_sizes; (void)n_in; (void)out_size; (void)ws_size;

  // x -> bf16
  k_cvt_x<<<48, 256, 0, stream>>>(x, xb, 64 * 768 / 4);
  // layer 1: (64x768)@(768x4096), K-split 3
  k_gemm<<<dim3(64, 3, 2), 256, 0, stream>>>(xb, 0L, w1g, w1s, partial, 4096, 768, 256);
  k_reduce_gelu<<<512, 256, 0, stream>>>(partial, b1g, b1s, h1b, 4096, 3, 2 * 64 * 4096 / 4);
  // layer 2: (64x4096)@(4096x4096), K-split 4
  k_gemm<<<dim3(64, 4, 2), 256, 0, stream>>>(h1b, (long)64 * 4096, w2g, w2s, partial, 4096, 4096, 1024);
  k_reduce_gelu<<<512, 256, 0, stream>>>(partial, b2g, b2s, h2b, 4096, 4, 2 * 64 * 4096 / 4);
  // layer 3: (64x4096)@(4096x256), K-split 32
  k_gemm<<<dim3(4, 32, 2), 256, 0, stream>>>(h2b, (long)64 * 4096, w3g, w3s, partial, 256, 4096, 128);
  // reduce + bias + expmap0 -> hyp bf16, y2
  k_expmap<<<dim3(64, 2), 256, 0, stream>>>(partial, b3g, b3s, hypb, y2, 32);
  // poincare distances -> logits
  k_dist<<<87, 256, 0, stream>>>(pg, ps, hypb, y2, out);
}